// Round 3
// baseline (1254.330 us; speedup 1.0000x reference)
//
#include <hip/hip_runtime.h>
#include <hip/hip_bf16.h>

typedef unsigned short u16;
typedef __attribute__((ext_vector_type(8))) short short8;
typedef __attribute__((ext_vector_type(4))) float f32x4;

#define NE 131072

// ws layout in u16 elements (bf16 transposed weights, [n][k] row-major)
#define OFF_WA 0        // 4 x [256][256]
#define OFF_WB 262144   // 4 x [128][256]
#define OFF_WF 393216   // 4 x [128][128]
#define OFF_WE 458752   // [128][32]
#define OFF_WS 462848   // [128]

// per-wave LDS slice (u16): H 16x264 = 4224 | G 16x136 = 2176 | cos 16 f32 = 32
#define SL_H   0
#define SL_G   4224
#define SL_COS 6400
#define SLICE  6432     // 12864 B per wave; 4 waves = 51456 B per block

__device__ __forceinline__ float b2f(u16 v) {
    unsigned int u = ((unsigned int)v) << 16;
    float f;
    __builtin_memcpy(&f, &u, 4);
    return f;
}
__device__ __forceinline__ u16 f2b(float f) {
    __hip_bfloat16 h = __float2bfloat16(f);
    u16 u;
    __builtin_memcpy(&u, &h, 2);
    return u;
}
__device__ __forceinline__ short8 pack8(float4 a, float4 b) {
    short8 p;
    p[0] = (short)f2b(a.x); p[1] = (short)f2b(a.y);
    p[2] = (short)f2b(a.z); p[3] = (short)f2b(a.w);
    p[4] = (short)f2b(b.x); p[5] = (short)f2b(b.y);
    p[6] = (short)f2b(b.z); p[7] = (short)f2b(b.w);
    return p;
}

#define MFMA16(a, b, c) __builtin_amdgcn_mfma_f32_16x16x32_bf16(a, b, c, 0, 0, 0)

struct BiasP {
    const float* ba[4];
    const float* bb[4];
};

__global__ void prep_kernel(const float* __restrict__ W1a, const float* __restrict__ W2a,
                            const float* __restrict__ W3a, const float* __restrict__ W4a,
                            const float* __restrict__ W1b, const float* __restrict__ W2b,
                            const float* __restrict__ W3b, const float* __restrict__ W4b,
                            const float* __restrict__ Wf,  u16* __restrict__ ws) {
    int y = blockIdx.y;
    int tid = blockIdx.x * 256 + threadIdx.x;
    if (y < 4) {
        if (tid < 65536) {
            const float* W = (y == 0) ? W1a : (y == 1) ? W2a : (y == 2) ? W3a : W4a;
            int n = tid & 255, k = tid >> 8;         // coalesced read, scattered write
            ws[OFF_WA + y * 65536 + n * 256 + k] = f2b(W[k * 256 + n]);
        }
    } else if (y < 8) {
        if (tid < 32768) {
            const float* W = (y == 4) ? W1b : (y == 5) ? W2b : (y == 6) ? W3b : W4b;
            int n = tid & 127, k = tid >> 7;
            ws[OFF_WB + (y - 4) * 32768 + n * 256 + k] = f2b(W[k * 128 + n]);
        }
    } else {
        if (tid < 69760) {                           // 545 * 128
            int n = tid & 127, k = tid >> 7;
            u16 v = f2b(Wf[k * 128 + n]);
            if (k < 512)       ws[OFF_WF + (k >> 7) * 16384 + n * 128 + (k & 127)] = v;
            else if (k == 512) ws[OFF_WS + n] = v;
            else               ws[OFF_WE + n * 32 + (k - 513)] = v;
        }
    }
}

__global__ __launch_bounds__(256, 2)
void fused_kernel(const float* __restrict__ x, const int* __restrict__ ei,
                  const float* __restrict__ ea, const u16* __restrict__ ws,
                  BiasP bp, const float* __restrict__ bfp, float* __restrict__ out) {
    __shared__ __align__(16) u16 lds[4 * SLICE];

    const int t = threadIdx.x;
    const int wave = t >> 6;
    const int lane = t & 63;
    const int l15 = lane & 15;
    const int g = lane >> 4;
    const int e0 = blockIdx.x * 64 + wave * 16;   // this wave's 16 edges

    u16* const sl  = &lds[wave * SLICE];
    u16* const pHs = sl + SL_H;                   // 16 x 264
    u16* const pGs = sl + SL_G;                   // 16 x 136
    float* const pcs = (float*)(sl + SL_COS);     // 16 f32

    const f32x4 zero4 = {0.f, 0.f, 0.f, 0.f};

    // Hedge: detect int64 edge_index (sampled high words all zero) vs int32.
    bool idx64 = true;
    #pragma unroll
    for (int i = 1; i < 16; i += 2) { idx64 = idx64 && (ei[i] == 0); }

    // ---- gather x_src/x_dst rows DIRECTLY into A-fragment registers ----
    // lane (g,l15) holds row l15, k = kk*32 + g*8 .. +8  (8 bf16 per kk)
    short8 srcF[8], dstF[8];
    {
        int ps = e0 + l15;
        int is = idx64 ? ei[2 * ps] : ei[ps];
        int id = idx64 ? ei[2 * (NE + ps)] : ei[NE + ps];
        const float* rs = x + (size_t)is * 256;
        const float* rd = x + (size_t)id * 256;
        float dot = 0.f, ss = 0.f, dd = 0.f;
        #pragma unroll
        for (int kk = 0; kk < 8; kk++) {
            int off = kk * 32 + g * 8;
            float4 sa = *(const float4*)(rs + off);
            float4 sb = *(const float4*)(rs + off + 4);
            float4 da = *(const float4*)(rd + off);
            float4 db = *(const float4*)(rd + off + 4);
            dot += sa.x * da.x + sa.y * da.y + sa.z * da.z + sa.w * da.w
                 + sb.x * db.x + sb.y * db.y + sb.z * db.z + sb.w * db.w;
            ss  += sa.x * sa.x + sa.y * sa.y + sa.z * sa.z + sa.w * sa.w
                 + sb.x * sb.x + sb.y * sb.y + sb.z * sb.z + sb.w * sb.w;
            dd  += da.x * da.x + da.y * da.y + da.z * da.z + da.w * da.w
                 + db.x * db.x + db.y * db.y + db.z * db.z + db.w * db.w;
            srcF[kk] = pack8(sa, sb);
            dstF[kk] = pack8(da, db);
        }
        // reduce across the 4 lanes holding the same row (lane ^ 16, ^ 32)
        dot += __shfl_xor(dot, 16); ss += __shfl_xor(ss, 16); dd += __shfl_xor(dd, 16);
        dot += __shfl_xor(dot, 32); ss += __shfl_xor(ss, 32); dd += __shfl_xor(dd, 32);
        if (g == 0) {
            float ns = fmaxf(sqrtf(ss), 1e-8f);
            float nd = fmaxf(sqrtf(dd), 1e-8f);
            pcs[l15] = dot / (ns * nd);
        }
    }
    __builtin_amdgcn_s_barrier();   // phase-lock waves for L1 weight reuse

    f32x4 Facc[8];
    #pragma unroll
    for (int a = 0; a < 8; a++) { Facc[a] = zero4; }

    #pragma unroll 1
    for (int m = 0; m < 4; m++) {
        const u16* wa = ws + OFF_WA + m * 65536;
        // ===== stage A: H = relu(A @ Wa + ba), two N-halves of 128 =====
        #pragma unroll 1
        for (int half = 0; half < 2; half++) {
            f32x4 acc[8];
            #pragma unroll
            for (int a = 0; a < 8; a++) { acc[a] = zero4; }
            #pragma unroll
            for (int kk = 0; kk < 8; kk++) {
                short8 af;
                if (m == 0)      af = srcF[kk];
                else if (m == 1) af = dstF[kk];
                else {
                    short8 s = srcF[kk], d = dstF[kk];
                    #pragma unroll
                    for (int j = 0; j < 8; j++) {
                        float fs = b2f((u16)s[j]);
                        float fd = b2f((u16)d[j]);
                        af[j] = (short)f2b((m == 2) ? (fs - fd) : (fs * fd));
                    }
                }
                const int k0 = kk * 32 + g * 8;
                #pragma unroll
                for (int nt = 0; nt < 8; nt++) {
                    int col = (half * 8 + nt) * 16 + l15;
                    short8 bf = *(const short8*)(wa + col * 256 + k0);
                    acc[nt] = MFMA16(af, bf, acc[nt]);
                }
            }
            const float* ba = bp.ba[m];
            #pragma unroll
            for (int nt = 0; nt < 8; nt++) {
                int col = (half * 8 + nt) * 16 + l15;
                float bias = ba[col];
                #pragma unroll
                for (int rg = 0; rg < 4; rg++) {
                    int row = g * 4 + rg;
                    pHs[row * 264 + col] = f2b(fmaxf(acc[nt][rg] + bias, 0.f));
                }
            }
        }
        __builtin_amdgcn_s_barrier();

        // ===== stage B: G = relu(H @ Wb + bb) =====
        {
            f32x4 acc[8];
            #pragma unroll
            for (int a = 0; a < 8; a++) { acc[a] = zero4; }
            const u16* wb = ws + OFF_WB + m * 32768;
            #pragma unroll
            for (int kk = 0; kk < 8; kk++) {
                const int k0 = kk * 32 + g * 8;
                short8 af = *(const short8*)(pHs + l15 * 264 + k0);
                #pragma unroll
                for (int nt = 0; nt < 8; nt++) {
                    int col = nt * 16 + l15;
                    short8 bf = *(const short8*)(wb + col * 256 + k0);
                    acc[nt] = MFMA16(af, bf, acc[nt]);
                }
            }
            const float* bb = bp.bb[m];
            #pragma unroll
            for (int nt = 0; nt < 8; nt++) {
                int col = nt * 16 + l15;
                float bias = bb[col];
                #pragma unroll
                for (int rg = 0; rg < 4; rg++) {
                    int row = g * 4 + rg;
                    pGs[row * 136 + col] = f2b(fmaxf(acc[nt][rg] + bias, 0.f));
                }
            }
        }
        __builtin_amdgcn_s_barrier();

        // ===== stage C: Facc += G @ WfT_m =====
        {
            const u16* wf = ws + OFF_WF + m * 16384;
            #pragma unroll
            for (int kk = 0; kk < 4; kk++) {
                const int k0 = kk * 32 + g * 8;
                short8 af = *(const short8*)(pGs + l15 * 136 + k0);
                #pragma unroll
                for (int nt = 0; nt < 8; nt++) {
                    int col = nt * 16 + l15;
                    short8 bf = *(const short8*)(wf + col * 128 + k0);
                    Facc[nt] = MFMA16(af, bf, Facc[nt]);
                }
            }
        }
        __builtin_amdgcn_s_barrier();
    }

    // ===== edge_attr contribution: Facc += EA @ WeT (K=32, direct-from-global frag) =====
    {
        const float* er = ea + (size_t)(e0 + l15) * 32 + g * 8;
        float4 a = *(const float4*)(er);
        float4 b = *(const float4*)(er + 4);
        short8 af = pack8(a, b);
        #pragma unroll
        for (int nt = 0; nt < 8; nt++) {
            int col = nt * 16 + l15;
            short8 bf = *(const short8*)(ws + OFF_WE + col * 32 + g * 8);
            Facc[nt] = MFMA16(af, bf, Facc[nt]);
        }
    }

    // ===== epilogue: + s*Wf[512] + bf, tanh, stage f32 in LDS (reuse H), store =====
    float* os = (float*)pHs;    // 16 rows x 132 f32 = 8448 B (exactly the H slice)
    #pragma unroll
    for (int nt = 0; nt < 8; nt++) {
        int col = nt * 16 + l15;
        float bv  = bfp[col];
        float wsr = b2f(ws[OFF_WS + col]);
        #pragma unroll
        for (int rg = 0; rg < 4; rg++) {
            int row = g * 4 + rg;
            float v = Facc[nt][rg] + pcs[row] * wsr + bv;
            v = fminf(fmaxf(v, -15.f), 15.f);
            float e2 = __expf(2.f * v);
            os[row * 132 + col] = (e2 - 1.f) / (e2 + 1.f);
        }
    }
    // within-wave LDS dependency; compiler inserts lgkmcnt. Coalesced store:
    {
        int row = lane >> 2, c = lane & 3;
        float* op = out + (size_t)(e0 + row) * 128 + c * 32;
        const float* sp = os + row * 132 + c * 32;
        #pragma unroll
        for (int i = 0; i < 8; i++) {
            float4 v = *(const float4*)(sp + i * 4);
            *(float4*)(op + i * 4) = v;
        }
    }
}

extern "C" void kernel_launch(void* const* d_in, const int* in_sizes, int n_in,
                              void* d_out, int out_size, void* d_ws, size_t ws_size,
                              hipStream_t stream) {
    u16* ws = (u16*)d_ws;
    prep_kernel<<<dim3(273, 9), 256, 0, stream>>>(
        (const float*)d_in[3],  (const float*)d_in[7],  (const float*)d_in[11], (const float*)d_in[15],
        (const float*)d_in[5],  (const float*)d_in[9],  (const float*)d_in[13], (const float*)d_in[17],
        (const float*)d_in[19], ws);

    BiasP bp;
    bp.ba[0] = (const float*)d_in[4];  bp.ba[1] = (const float*)d_in[8];
    bp.ba[2] = (const float*)d_in[12]; bp.ba[3] = (const float*)d_in[16];
    bp.bb[0] = (const float*)d_in[6];  bp.bb[1] = (const float*)d_in[10];
    bp.bb[2] = (const float*)d_in[14]; bp.bb[3] = (const float*)d_in[18];

    fused_kernel<<<NE / 64, 256, 0, stream>>>(
        (const float*)d_in[0], (const int*)d_in[1], (const float*)d_in[2], ws,
        bp, (const float*)d_in[20], (float*)d_out);
}

// Round 4
// 623.994 us; speedup vs baseline: 2.0102x; 2.0102x over previous
//
#include <hip/hip_runtime.h>
#include <hip/hip_bf16.h>

typedef unsigned short u16;
typedef __attribute__((ext_vector_type(8))) short short8;
typedef __attribute__((ext_vector_type(4))) float f32x4;
typedef __attribute__((ext_vector_type(4))) unsigned short u16x4;

#define NE 131072

// ws layout in u16 elements (bf16 transposed weights, [n][k] row-major)
#define OFF_WA 0        // 4 x [256][256]
#define OFF_WB 262144   // 4 x [128][256]
#define OFF_WF 393216   // 4 x [128][128]
#define OFF_WE 458752   // [128][32]
#define OFF_WS 462848   // [128]

__device__ __forceinline__ float b2f(u16 v) {
    unsigned int u = ((unsigned int)v) << 16;
    float f;
    __builtin_memcpy(&f, &u, 4);
    return f;
}
__device__ __forceinline__ u16 f2b(float f) {
    __hip_bfloat16 h = __float2bfloat16(f);
    u16 u;
    __builtin_memcpy(&u, &h, 2);
    return u;
}
__device__ __forceinline__ short8 pack8(float4 a, float4 b) {
    short8 p;
    p[0] = (short)f2b(a.x); p[1] = (short)f2b(a.y);
    p[2] = (short)f2b(a.z); p[3] = (short)f2b(a.w);
    p[4] = (short)f2b(b.x); p[5] = (short)f2b(b.y);
    p[6] = (short)f2b(b.z); p[7] = (short)f2b(b.w);
    return p;
}

#define MFMA16(a, b, c) __builtin_amdgcn_mfma_f32_16x16x32_bf16(a, b, c, 0, 0, 0)

struct BiasP {
    const float* ba[4];
    const float* bb[4];
};

__global__ void prep_kernel(const float* __restrict__ W1a, const float* __restrict__ W2a,
                            const float* __restrict__ W3a, const float* __restrict__ W4a,
                            const float* __restrict__ W1b, const float* __restrict__ W2b,
                            const float* __restrict__ W3b, const float* __restrict__ W4b,
                            const float* __restrict__ Wf,  u16* __restrict__ ws) {
    int y = blockIdx.y;
    int tid = blockIdx.x * 256 + threadIdx.x;
    if (y < 4) {
        if (tid < 65536) {
            const float* W = (y == 0) ? W1a : (y == 1) ? W2a : (y == 2) ? W3a : W4a;
            int n = tid & 255, k = tid >> 8;         // coalesced read, scattered write
            ws[OFF_WA + y * 65536 + n * 256 + k] = f2b(W[k * 256 + n]);
        }
    } else if (y < 8) {
        if (tid < 32768) {
            const float* W = (y == 4) ? W1b : (y == 5) ? W2b : (y == 6) ? W3b : W4b;
            int n = tid & 127, k = tid >> 7;
            ws[OFF_WB + (y - 4) * 32768 + n * 256 + k] = f2b(W[k * 128 + n]);
        }
    } else {
        if (tid < 69760) {                           // 545 * 128
            int n = tid & 127, k = tid >> 7;
            u16 v = f2b(Wf[k * 128 + n]);
            if (k < 512)       ws[OFF_WF + (k >> 7) * 16384 + n * 128 + (k & 127)] = v;
            else if (k == 512) ws[OFF_WS + n] = v;
            else               ws[OFF_WE + n * 32 + (k - 513)] = v;
        }
    }
}

// 32 edges per block; LDS ~62 KB -> 2 blocks/CU (8 waves/CU).
__global__ __launch_bounds__(256)
void fused_kernel(const float* __restrict__ x, const int* __restrict__ ei,
                  const float* __restrict__ ea, const u16* __restrict__ ws,
                  BiasP bp, const float* __restrict__ bfp, float* __restrict__ out) {
    __shared__ __align__(16) u16 Xs[32][264];
    __shared__ __align__(16) u16 Xd[32][264];
    __shared__ __align__(16) u16 Hs[32][264];
    __shared__ __align__(16) u16 Gs[32][136];
    __shared__ __align__(16) u16 EAs[32][40];
    __shared__ float scos[32];

    const int t = threadIdx.x;
    const int wave = t >> 6;
    const int lane = t & 63;
    const int l15 = lane & 15;
    const int g = lane >> 4;
    const int e0 = blockIdx.x * 32;

    const f32x4 zero4 = {0.f, 0.f, 0.f, 0.f};

    // Hedge: detect int64 edge_index (sampled high words all zero) vs int32.
    bool idx64 = true;
    #pragma unroll
    for (int i = 1; i < 16; i += 2) { idx64 = idx64 && (ei[i] == 0); }

    // ---- gather x rows (f32 -> bf16) + edge_attr tile into LDS ----
    {
        int r = t >> 2;              // 0..63 : 32 src rows then 32 dst rows
        int q = t & 3;               // quarter of the 256-wide row
        int er = r & 31;
        int pos = ((r < 32) ? 0 : NE) + e0 + er;
        int idx = idx64 ? ei[2 * pos] : ei[pos];
        const float* src = x + (size_t)idx * 256 + q * 64;
        u16* dl = (r < 32) ? &Xs[er][q * 64] : &Xd[er][q * 64];
        #pragma unroll
        for (int i = 0; i < 8; i++) {
            float4 a = *(const float4*)(src + i * 8);
            float4 b = *(const float4*)(src + i * 8 + 4);
            *(short8*)(dl + i * 8) = pack8(a, b);
        }
        // edge_attr: 32 edges x 32 f32; thread -> (edge = t>>3, 4 floats)
        int edge = t >> 3, c = t & 7;
        float4 v = *(const float4*)(ea + (size_t)(e0 + edge) * 32 + c * 4);
        u16x4 p;
        p[0] = f2b(v.x); p[1] = f2b(v.y); p[2] = f2b(v.z); p[3] = f2b(v.w);
        *(u16x4*)(&EAs[edge][c * 4]) = p;
    }
    __syncthreads();

    // ---- cosine similarity: 8 threads per edge, shuffle-reduce ----
    {
        int edge = t >> 3, q = t & 7;
        float dot = 0.f, ss = 0.f, dd = 0.f;
        #pragma unroll
        for (int i = 0; i < 8; i++) {
            int k = q * 32 + i * 4;
            u16x4 a = *(const u16x4*)&Xs[edge][k];
            u16x4 b = *(const u16x4*)&Xd[edge][k];
            #pragma unroll
            for (int j = 0; j < 4; j++) {
                float fa = b2f(a[j]);
                float fb = b2f(b[j]);
                dot += fa * fb;
                ss  += fa * fa;
                dd  += fb * fb;
            }
        }
        dot += __shfl_xor(dot, 1); ss += __shfl_xor(ss, 1); dd += __shfl_xor(dd, 1);
        dot += __shfl_xor(dot, 2); ss += __shfl_xor(ss, 2); dd += __shfl_xor(dd, 2);
        dot += __shfl_xor(dot, 4); ss += __shfl_xor(ss, 4); dd += __shfl_xor(dd, 4);
        if (q == 0) {
            float ns = fmaxf(sqrtf(ss), 1e-8f);
            float nd = fmaxf(sqrtf(dd), 1e-8f);
            scos[edge] = dot / (ns * nd);
        }
    }

    f32x4 Facc[2][2];
    #pragma unroll
    for (int a = 0; a < 2; a++) {
        #pragma unroll
        for (int b = 0; b < 2; b++) { Facc[a][b] = zero4; }
    }

    const int colA = wave * 64;   // stage A: wave owns 64 of 256 cols
    const int colC = wave * 32;   // stage B/C: wave owns 32 of 128 cols

    #pragma unroll 1
    for (int m = 0; m < 4; m++) {
        // ===== stage A: H = relu(A @ Wa + ba); A in {Xs, Xd, Xs-Xd, Xs*Xd} =====
        f32x4 accA[2][4];
        #pragma unroll
        for (int a = 0; a < 2; a++) {
            #pragma unroll
            for (int b = 0; b < 4; b++) { accA[a][b] = zero4; }
        }
        const u16* wa = ws + OFF_WA + m * 65536;
        #pragma unroll
        for (int kk = 0; kk < 8; kk++) {
            const int k0 = kk * 32 + g * 8;
            short8 afr[2];
            short8 bfr[4];
            #pragma unroll
            for (int mt = 0; mt < 2; mt++) {
                const int rowi = mt * 16 + l15;
                if (m == 0) {
                    afr[mt] = *(const short8*)&Xs[rowi][k0];
                } else if (m == 1) {
                    afr[mt] = *(const short8*)&Xd[rowi][k0];
                } else {
                    short8 sa = *(const short8*)&Xs[rowi][k0];
                    short8 sd = *(const short8*)&Xd[rowi][k0];
                    short8 rr;
                    #pragma unroll
                    for (int j = 0; j < 8; j++) {
                        float fs = b2f((u16)sa[j]);
                        float fd = b2f((u16)sd[j]);
                        float v = (m == 2) ? (fs - fd) : (fs * fd);
                        rr[j] = (short)f2b(v);
                    }
                    afr[mt] = rr;
                }
            }
            #pragma unroll
            for (int nt = 0; nt < 4; nt++) {
                int col = colA + nt * 16 + l15;
                bfr[nt] = *(const short8*)(wa + col * 256 + k0);
            }
            #pragma unroll
            for (int mt = 0; mt < 2; mt++) {
                #pragma unroll
                for (int nt = 0; nt < 4; nt++) {
                    accA[mt][nt] = MFMA16(afr[mt], bfr[nt], accA[mt][nt]);
                }
            }
        }
        {
            const float* ba = bp.ba[m];
            #pragma unroll
            for (int nt = 0; nt < 4; nt++) {
                int col = colA + nt * 16 + l15;
                float bias = ba[col];
                #pragma unroll
                for (int mt = 0; mt < 2; mt++) {
                    #pragma unroll
                    for (int rg = 0; rg < 4; rg++) {
                        int row = mt * 16 + g * 4 + rg;
                        Hs[row][col] = f2b(fmaxf(accA[mt][nt][rg] + bias, 0.f));
                    }
                }
            }
        }
        __syncthreads();

        // ===== stage B: G = relu(H @ Wb + bb) =====
        f32x4 accB[2][2];
        #pragma unroll
        for (int a = 0; a < 2; a++) {
            #pragma unroll
            for (int b = 0; b < 2; b++) { accB[a][b] = zero4; }
        }
        const u16* wb = ws + OFF_WB + m * 32768;
        #pragma unroll
        for (int kk = 0; kk < 8; kk++) {
            const int k0 = kk * 32 + g * 8;
            short8 afr[2];
            short8 bfr[2];
            #pragma unroll
            for (int mt = 0; mt < 2; mt++) {
                afr[mt] = *(const short8*)&Hs[mt * 16 + l15][k0];
            }
            #pragma unroll
            for (int nt = 0; nt < 2; nt++) {
                int col = colC + nt * 16 + l15;
                bfr[nt] = *(const short8*)(wb + col * 256 + k0);
            }
            #pragma unroll
            for (int mt = 0; mt < 2; mt++) {
                #pragma unroll
                for (int nt = 0; nt < 2; nt++) {
                    accB[mt][nt] = MFMA16(afr[mt], bfr[nt], accB[mt][nt]);
                }
            }
        }
        {
            const float* bb = bp.bb[m];
            #pragma unroll
            for (int nt = 0; nt < 2; nt++) {
                int col = colC + nt * 16 + l15;
                float bias = bb[col];
                #pragma unroll
                for (int mt = 0; mt < 2; mt++) {
                    #pragma unroll
                    for (int rg = 0; rg < 4; rg++) {
                        int row = mt * 16 + g * 4 + rg;
                        Gs[row][col] = f2b(fmaxf(accB[mt][nt][rg] + bias, 0.f));
                    }
                }
            }
        }
        __syncthreads();

        // ===== stage C: Facc += G @ WfT_m  (no trailing barrier needed:
        // next-A's barrier orders these Gs reads before next-B's Gs writes) =====
        const u16* wf = ws + OFF_WF + m * 16384;
        #pragma unroll
        for (int kk = 0; kk < 4; kk++) {
            const int k0 = kk * 32 + g * 8;
            short8 afr[2];
            short8 bfr[2];
            #pragma unroll
            for (int mt = 0; mt < 2; mt++) {
                afr[mt] = *(const short8*)&Gs[mt * 16 + l15][k0];
            }
            #pragma unroll
            for (int nt = 0; nt < 2; nt++) {
                int col = colC + nt * 16 + l15;
                bfr[nt] = *(const short8*)(wf + col * 128 + k0);
            }
            #pragma unroll
            for (int mt = 0; mt < 2; mt++) {
                #pragma unroll
                for (int nt = 0; nt < 2; nt++) {
                    Facc[mt][nt] = MFMA16(afr[mt], bfr[nt], Facc[mt][nt]);
                }
            }
        }
    }

    // ===== edge_attr contribution: Facc += EA @ WeT (K=32, one iter) =====
    {
        const int k0 = g * 8;
        short8 afr[2];
        short8 bfr[2];
        #pragma unroll
        for (int mt = 0; mt < 2; mt++) {
            afr[mt] = *(const short8*)&EAs[mt * 16 + l15][k0];
        }
        #pragma unroll
        for (int nt = 0; nt < 2; nt++) {
            int col = colC + nt * 16 + l15;
            bfr[nt] = *(const short8*)(ws + OFF_WE + col * 32 + k0);
        }
        #pragma unroll
        for (int mt = 0; mt < 2; mt++) {
            #pragma unroll
            for (int nt = 0; nt < 2; nt++) {
                Facc[mt][nt] = MFMA16(afr[mt], bfr[nt], Facc[mt][nt]);
            }
        }
    }

    // ===== epilogue: + s*Wf[512] + bf, tanh, stage f32 in LDS, coalesced store =====
    float* os = (float*)&Xs[0][0];   // reuse Xs: 32 rows x 132 f32 = 16896 B (exact fit)
    #pragma unroll
    for (int nt = 0; nt < 2; nt++) {
        int col = colC + nt * 16 + l15;
        float bv  = bfp[col];
        float wsr = b2f(ws[OFF_WS + col]);
        #pragma unroll
        for (int mt = 0; mt < 2; mt++) {
            #pragma unroll
            for (int rg = 0; rg < 4; rg++) {
                int row = mt * 16 + g * 4 + rg;
                float v = Facc[mt][nt][rg] + scos[row] * wsr + bv;
                v = fminf(fmaxf(v, -15.f), 15.f);
                float e2 = __expf(2.f * v);
                os[row * 132 + col] = (e2 - 1.f) / (e2 + 1.f);
            }
        }
    }
    __syncthreads();
    {
        int row = t >> 3, c = t & 7;
        float* op = out + (size_t)(e0 + row) * 128 + c * 16;
        const float* sp = os + row * 132 + c * 16;
        #pragma unroll
        for (int i = 0; i < 4; i++) {
            float4 v = *(const float4*)(sp + i * 4);
            *(float4*)(op + i * 4) = v;
        }
    }
}

extern "C" void kernel_launch(void* const* d_in, const int* in_sizes, int n_in,
                              void* d_out, int out_size, void* d_ws, size_t ws_size,
                              hipStream_t stream) {
    u16* ws = (u16*)d_ws;
    prep_kernel<<<dim3(273, 9), 256, 0, stream>>>(
        (const float*)d_in[3],  (const float*)d_in[7],  (const float*)d_in[11], (const float*)d_in[15],
        (const float*)d_in[5],  (const float*)d_in[9],  (const float*)d_in[13], (const float*)d_in[17],
        (const float*)d_in[19], ws);

    BiasP bp;
    bp.ba[0] = (const float*)d_in[4];  bp.ba[1] = (const float*)d_in[8];
    bp.ba[2] = (const float*)d_in[12]; bp.ba[3] = (const float*)d_in[16];
    bp.bb[0] = (const float*)d_in[6];  bp.bb[1] = (const float*)d_in[10];
    bp.bb[2] = (const float*)d_in[14]; bp.bb[3] = (const float*)d_in[18];

    fused_kernel<<<NE / 32, 256, 0, stream>>>(
        (const float*)d_in[0], (const int*)d_in[1], (const float*)d_in[2], ws,
        bp, (const float*)d_in[20], (float*)d_out);
}

// Round 5
// 614.858 us; speedup vs baseline: 2.0400x; 1.0149x over previous
//
#include <hip/hip_runtime.h>
#include <hip/hip_bf16.h>

typedef unsigned short u16;
typedef __attribute__((ext_vector_type(8))) short short8;
typedef __attribute__((ext_vector_type(4))) float f32x4;

#define NE 131072

// ws layout in u16 elements (bf16 transposed weights, [n][k] row-major)
#define OFF_WA 0        // 4 x [256][256]
#define OFF_WB 262144   // 4 x [128][256]
#define OFF_WF 393216   // 4 x [128][128]
#define OFF_WE 458752   // [128][32]
#define OFF_WS 462848   // [128]

__device__ __forceinline__ float b2f(u16 v) {
    unsigned int u = ((unsigned int)v) << 16;
    float f;
    __builtin_memcpy(&f, &u, 4);
    return f;
}
__device__ __forceinline__ u16 f2b(float f) {
    __hip_bfloat16 h = __float2bfloat16(f);
    u16 u;
    __builtin_memcpy(&u, &h, 2);
    return u;
}
__device__ __forceinline__ short8 pack8(float4 a, float4 b) {
    short8 p;
    p[0] = (short)f2b(a.x); p[1] = (short)f2b(a.y);
    p[2] = (short)f2b(a.z); p[3] = (short)f2b(a.w);
    p[4] = (short)f2b(b.x); p[5] = (short)f2b(b.y);
    p[6] = (short)f2b(b.z); p[7] = (short)f2b(b.w);
    return p;
}

#define MFMA16(a, b, c) __builtin_amdgcn_mfma_f32_16x16x32_bf16(a, b, c, 0, 0, 0)

struct BiasP {
    const float* ba[4];
    const float* bb[4];
};

__global__ void prep_kernel(const float* __restrict__ W1a, const float* __restrict__ W2a,
                            const float* __restrict__ W3a, const float* __restrict__ W4a,
                            const float* __restrict__ W1b, const float* __restrict__ W2b,
                            const float* __restrict__ W3b, const float* __restrict__ W4b,
                            const float* __restrict__ Wf,  u16* __restrict__ ws) {
    int y = blockIdx.y;
    int tid = blockIdx.x * 256 + threadIdx.x;
    if (y < 4) {
        if (tid < 65536) {
            const float* W = (y == 0) ? W1a : (y == 1) ? W2a : (y == 2) ? W3a : W4a;
            int n = tid & 255, k = tid >> 8;         // coalesced read, scattered write
            ws[OFF_WA + y * 65536 + n * 256 + k] = f2b(W[k * 256 + n]);
        }
    } else if (y < 8) {
        if (tid < 32768) {
            const float* W = (y == 4) ? W1b : (y == 5) ? W2b : (y == 6) ? W3b : W4b;
            int n = tid & 127, k = tid >> 7;
            ws[OFF_WB + (y - 4) * 32768 + n * 256 + k] = f2b(W[k * 128 + n]);
        }
    } else {
        if (tid < 69760) {                           // 545 * 128
            int n = tid & 127, k = tid >> 7;
            u16 v = f2b(Wf[k * 128 + n]);
            if (k < 512)       ws[OFF_WF + (k >> 7) * 16384 + n * 128 + (k & 127)] = v;
            else if (k == 512) ws[OFF_WS + n] = v;
            else               ws[OFF_WE + n * 32 + (k - 513)] = v;
        }
    }
}

// 32 edges per block; LDS ~60 KB -> 2 blocks/CU (8 waves/CU).
__global__ __launch_bounds__(256)
void fused_kernel(const float* __restrict__ x, const int* __restrict__ ei,
                  const float* __restrict__ ea, const u16* __restrict__ ws,
                  BiasP bp, const float* __restrict__ bfp, float* __restrict__ out) {
    __shared__ __align__(16) u16 Xs[32][264];
    __shared__ __align__(16) u16 Xd[32][264];
    __shared__ __align__(16) u16 Hs[32][264];
    __shared__ __align__(16) u16 Gs[32][136];
    __shared__ float scos[32];

    const int t = threadIdx.x;
    const int wave = t >> 6;
    const int lane = t & 63;
    const int l15 = lane & 15;
    const int g = lane >> 4;
    const int e0 = blockIdx.x * 32;

    const f32x4 zero4 = {0.f, 0.f, 0.f, 0.f};

    // Hedge: detect int64 edge_index (sampled high words all zero) vs int32.
    bool idx64 = true;
    #pragma unroll
    for (int i = 1; i < 16; i += 2) { idx64 = idx64 && (ei[i] == 0); }

    // ---- gather (f32 -> bf16 tiles) + cosine similarity in one pass ----
    {
        int edge = t >> 3;            // 0..31
        int c = t & 7;                // 32-float chunk of the 256-row
        int pos = e0 + edge;
        int is = idx64 ? ei[2 * pos] : ei[pos];
        int id = idx64 ? ei[2 * (NE + pos)] : ei[NE + pos];
        const float* rs = x + (size_t)is * 256 + c * 32;
        const float* rd = x + (size_t)id * 256 + c * 32;
        float dot = 0.f, ss = 0.f, dd = 0.f;
        #pragma unroll
        for (int i = 0; i < 4; i++) {
            float4 s0 = *(const float4*)(rs + i * 8);
            float4 s1 = *(const float4*)(rs + i * 8 + 4);
            float4 d0 = *(const float4*)(rd + i * 8);
            float4 d1 = *(const float4*)(rd + i * 8 + 4);
            dot += s0.x * d0.x + s0.y * d0.y + s0.z * d0.z + s0.w * d0.w
                 + s1.x * d1.x + s1.y * d1.y + s1.z * d1.z + s1.w * d1.w;
            ss  += s0.x * s0.x + s0.y * s0.y + s0.z * s0.z + s0.w * s0.w
                 + s1.x * s1.x + s1.y * s1.y + s1.z * s1.z + s1.w * s1.w;
            dd  += d0.x * d0.x + d0.y * d0.y + d0.z * d0.z + d0.w * d0.w
                 + d1.x * d1.x + d1.y * d1.y + d1.z * d1.z + d1.w * d1.w;
            *(short8*)(&Xs[edge][c * 32 + i * 8]) = pack8(s0, s1);
            *(short8*)(&Xd[edge][c * 32 + i * 8]) = pack8(d0, d1);
        }
        dot += __shfl_xor(dot, 1); ss += __shfl_xor(ss, 1); dd += __shfl_xor(dd, 1);
        dot += __shfl_xor(dot, 2); ss += __shfl_xor(ss, 2); dd += __shfl_xor(dd, 2);
        dot += __shfl_xor(dot, 4); ss += __shfl_xor(ss, 4); dd += __shfl_xor(dd, 4);
        if (c == 0) {
            float ns = fmaxf(sqrtf(ss), 1e-8f);
            float nd = fmaxf(sqrtf(dd), 1e-8f);
            scos[edge] = dot / (ns * nd);
        }
    }
    __syncthreads();

    const int colA = wave * 64;   // stage A: wave owns 64 of 256 cols
    const int colC = wave * 32;   // stage B/C: wave owns 32 of 128 cols

    // ---- pre-issue long-lived fragments/constants (consumed after the m-loop) ----
    short8 eaA[2];
    #pragma unroll
    for (int mt = 0; mt < 2; mt++) {
        const float* er = ea + (size_t)(e0 + mt * 16 + l15) * 32 + g * 8;
        float4 a = *(const float4*)(er);
        float4 b = *(const float4*)(er + 4);
        eaA[mt] = pack8(a, b);
    }
    short8 eaB[2];
    float epi_b[2], epi_w[2];
    #pragma unroll
    for (int nt = 0; nt < 2; nt++) {
        int col = colC + nt * 16 + l15;
        eaB[nt] = *(const short8*)(ws + OFF_WE + col * 32 + g * 8);
        epi_b[nt] = bfp[col];
        epi_w[nt] = b2f(ws[OFF_WS + col]);
    }

    // ---- LDS read base pointers (immediate kk*64B offsets from here) ----
    const u16* xsb[2]; const u16* xdb[2]; const u16* hrb[2]; const u16* grb[2];
    #pragma unroll
    for (int mt = 0; mt < 2; mt++) {
        xsb[mt] = &Xs[mt * 16 + l15][g * 8];
        xdb[mt] = &Xd[mt * 16 + l15][g * 8];
        hrb[mt] = &Hs[mt * 16 + l15][g * 8];
        grb[mt] = &Gs[mt * 16 + l15][g * 8];
    }

    f32x4 Facc[2][2];
    #pragma unroll
    for (int a = 0; a < 2; a++) {
        #pragma unroll
        for (int b = 0; b < 2; b++) { Facc[a][b] = zero4; }
    }

    #pragma unroll 1
    for (int m = 0; m < 4; m++) {
        // ===== stage A: H = relu(A @ Wa + ba); A in {Xs, Xd, Xs-Xd, Xs*Xd} =====
        const u16* wan[4];
        #pragma unroll
        for (int nt = 0; nt < 4; nt++) {
            wan[nt] = ws + OFF_WA + m * 65536 + (size_t)(colA + nt * 16 + l15) * 256 + g * 8;
        }
        float biasA[4];
        #pragma unroll
        for (int nt = 0; nt < 4; nt++) { biasA[nt] = bp.ba[m][colA + nt * 16 + l15]; }

        f32x4 accA[2][4];
        #pragma unroll
        for (int a = 0; a < 2; a++) {
            #pragma unroll
            for (int b = 0; b < 4; b++) { accA[a][b] = zero4; }
        }

        short8 bB[2][4], rs_[2][2], rd_[2][2];
        #pragma unroll
        for (int nt = 0; nt < 4; nt++) { bB[0][nt] = *(const short8*)(wan[nt]); }
        #pragma unroll
        for (int mt = 0; mt < 2; mt++) {
            rs_[0][mt] = *(const short8*)(xsb[mt]);
            rd_[0][mt] = *(const short8*)(xdb[mt]);
        }
        #pragma unroll
        for (int kk = 0; kk < 8; kk++) {
            const int cur = kk & 1, nxt = cur ^ 1;
            if (kk < 7) {   // prefetch kk+1 (double-buffer, loads ahead of MFMAs)
                #pragma unroll
                for (int nt = 0; nt < 4; nt++) {
                    bB[nxt][nt] = *(const short8*)(wan[nt] + (kk + 1) * 32);
                }
                #pragma unroll
                for (int mt = 0; mt < 2; mt++) {
                    rs_[nxt][mt] = *(const short8*)(xsb[mt] + (kk + 1) * 32);
                    rd_[nxt][mt] = *(const short8*)(xdb[mt] + (kk + 1) * 32);
                }
            }
            short8 af[2];
            if (m == 0) {
                af[0] = rs_[cur][0]; af[1] = rs_[cur][1];
            } else if (m == 1) {
                af[0] = rd_[cur][0]; af[1] = rd_[cur][1];
            } else {
                #pragma unroll
                for (int mt = 0; mt < 2; mt++) {
                    short8 s = rs_[cur][mt], d = rd_[cur][mt], rr;
                    #pragma unroll
                    for (int j = 0; j < 8; j++) {
                        float fs = b2f((u16)s[j]);
                        float fd = b2f((u16)d[j]);
                        rr[j] = (short)f2b((m == 2) ? (fs - fd) : (fs * fd));
                    }
                    af[mt] = rr;
                }
            }
            #pragma unroll
            for (int mt = 0; mt < 2; mt++) {
                #pragma unroll
                for (int nt = 0; nt < 4; nt++) {
                    accA[mt][nt] = MFMA16(af[mt], bB[cur][nt], accA[mt][nt]);
                }
            }
        }
        #pragma unroll
        for (int nt = 0; nt < 4; nt++) {
            int col = colA + nt * 16 + l15;
            #pragma unroll
            for (int mt = 0; mt < 2; mt++) {
                #pragma unroll
                for (int rg = 0; rg < 4; rg++) {
                    int row = mt * 16 + g * 4 + rg;
                    Hs[row][col] = f2b(fmaxf(accA[mt][nt][rg] + biasA[nt], 0.f));
                }
            }
        }
        __syncthreads();

        // ===== stage B: G = relu(H @ Wb + bb) — full weight hoist (16 loads) =====
        {
            const u16* wbn[2];
            #pragma unroll
            for (int nt = 0; nt < 2; nt++) {
                wbn[nt] = ws + OFF_WB + m * 32768 + (size_t)(colC + nt * 16 + l15) * 256 + g * 8;
            }
            float biasB[2];
            #pragma unroll
            for (int nt = 0; nt < 2; nt++) { biasB[nt] = bp.bb[m][colC + nt * 16 + l15]; }

            short8 wB[8][2];
            #pragma unroll
            for (int kk = 0; kk < 8; kk++) {
                #pragma unroll
                for (int nt = 0; nt < 2; nt++) {
                    wB[kk][nt] = *(const short8*)(wbn[nt] + kk * 32);
                }
            }
            f32x4 accB[2][2];
            #pragma unroll
            for (int a = 0; a < 2; a++) {
                #pragma unroll
                for (int b = 0; b < 2; b++) { accB[a][b] = zero4; }
            }
            short8 hA[2][2];
            #pragma unroll
            for (int mt = 0; mt < 2; mt++) { hA[0][mt] = *(const short8*)(hrb[mt]); }
            #pragma unroll
            for (int kk = 0; kk < 8; kk++) {
                const int cur = kk & 1, nxt = cur ^ 1;
                if (kk < 7) {
                    #pragma unroll
                    for (int mt = 0; mt < 2; mt++) {
                        hA[nxt][mt] = *(const short8*)(hrb[mt] + (kk + 1) * 32);
                    }
                }
                #pragma unroll
                for (int mt = 0; mt < 2; mt++) {
                    #pragma unroll
                    for (int nt = 0; nt < 2; nt++) {
                        accB[mt][nt] = MFMA16(hA[cur][mt], wB[kk][nt], accB[mt][nt]);
                    }
                }
            }
            #pragma unroll
            for (int nt = 0; nt < 2; nt++) {
                int col = colC + nt * 16 + l15;
                #pragma unroll
                for (int mt = 0; mt < 2; mt++) {
                    #pragma unroll
                    for (int rg = 0; rg < 4; rg++) {
                        int row = mt * 16 + g * 4 + rg;
                        Gs[row][col] = f2b(fmaxf(accB[mt][nt][rg] + biasB[nt], 0.f));
                    }
                }
            }
        }
        __syncthreads();

        // ===== stage C: Facc += G @ WfT_m — full weight hoist (8 loads).
        // (no trailing barrier: next-A's barrier orders Gs reads vs next-B writes) =====
        {
            const u16* wfn[2];
            #pragma unroll
            for (int nt = 0; nt < 2; nt++) {
                wfn[nt] = ws + OFF_WF + m * 16384 + (size_t)(colC + nt * 16 + l15) * 128 + g * 8;
            }
            short8 wF[4][2];
            #pragma unroll
            for (int kk = 0; kk < 4; kk++) {
                #pragma unroll
                for (int nt = 0; nt < 2; nt++) {
                    wF[kk][nt] = *(const short8*)(wfn[nt] + kk * 32);
                }
            }
            short8 gA[2][2];
            #pragma unroll
            for (int mt = 0; mt < 2; mt++) { gA[0][mt] = *(const short8*)(grb[mt]); }
            #pragma unroll
            for (int kk = 0; kk < 4; kk++) {
                const int cur = kk & 1, nxt = cur ^ 1;
                if (kk < 3) {
                    #pragma unroll
                    for (int mt = 0; mt < 2; mt++) {
                        gA[nxt][mt] = *(const short8*)(grb[mt] + (kk + 1) * 32);
                    }
                }
                #pragma unroll
                for (int mt = 0; mt < 2; mt++) {
                    #pragma unroll
                    for (int nt = 0; nt < 2; nt++) {
                        Facc[mt][nt] = MFMA16(gA[cur][mt], wF[kk][nt], Facc[mt][nt]);
                    }
                }
            }
        }
    }

    // ===== edge_attr contribution: Facc += EA @ WeT (fragments pre-loaded) =====
    #pragma unroll
    for (int mt = 0; mt < 2; mt++) {
        #pragma unroll
        for (int nt = 0; nt < 2; nt++) {
            Facc[mt][nt] = MFMA16(eaA[mt], eaB[nt], Facc[mt][nt]);
        }
    }

    // ===== epilogue: + s*Wf[512] + bf, tanh, stage f32 in LDS, coalesced store =====
    float* os = (float*)&Xs[0][0];   // reuse Xs: 32 rows x 132 f32 = 16896 B (exact fit)
    #pragma unroll
    for (int nt = 0; nt < 2; nt++) {
        int col = colC + nt * 16 + l15;
        #pragma unroll
        for (int mt = 0; mt < 2; mt++) {
            #pragma unroll
            for (int rg = 0; rg < 4; rg++) {
                int row = mt * 16 + g * 4 + rg;
                float v = Facc[mt][nt][rg] + scos[row] * epi_w[nt] + epi_b[nt];
                v = fminf(fmaxf(v, -15.f), 15.f);
                float e2 = __expf(2.f * v);
                os[row * 132 + col] = (e2 - 1.f) / (e2 + 1.f);
            }
        }
    }
    __syncthreads();
    {
        int row = t >> 3, c = t & 7;
        float* op = out + (size_t)(e0 + row) * 128 + c * 16;
        const float* sp = os + row * 132 + c * 16;
        #pragma unroll
        for (int i = 0; i < 4; i++) {
            float4 v = *(const float4*)(sp + i * 4);
            *(float4*)(op + i * 4) = v;
        }
    }
}

extern "C" void kernel_launch(void* const* d_in, const int* in_sizes, int n_in,
                              void* d_out, int out_size, void* d_ws, size_t ws_size,
                              hipStream_t stream) {
    u16* ws = (u16*)d_ws;
    prep_kernel<<<dim3(273, 9), 256, 0, stream>>>(
        (const float*)d_in[3],  (const float*)d_in[7],  (const float*)d_in[11], (const float*)d_in[15],
        (const float*)d_in[5],  (const float*)d_in[9],  (const float*)d_in[13], (const float*)d_in[17],
        (const float*)d_in[19], ws);

    BiasP bp;
    bp.ba[0] = (const float*)d_in[4];  bp.ba[1] = (const float*)d_in[8];
    bp.ba[2] = (const float*)d_in[12]; bp.ba[3] = (const float*)d_in[16];
    bp.bb[0] = (const float*)d_in[6];  bp.bb[1] = (const float*)d_in[10];
    bp.bb[2] = (const float*)d_in[14]; bp.bb[3] = (const float*)d_in[18];

    fused_kernel<<<NE / 32, 256, 0, stream>>>(
        (const float*)d_in[0], (const int*)d_in[1], (const float*)d_in[2], ws,
        bp, (const float*)d_in[20], (float*)d_out);
}

// Round 6
// 612.075 us; speedup vs baseline: 2.0493x; 1.0045x over previous
//
#include <hip/hip_runtime.h>
#include <hip/hip_bf16.h>

typedef unsigned short u16;
typedef __attribute__((ext_vector_type(8))) short short8;
typedef __attribute__((ext_vector_type(4))) float f32x4;

#define NE 131072

// ws layout in u16 elements (bf16 transposed weights, [n][k] row-major)
#define OFF_WA 0        // 4 x [256][256]
#define OFF_WB 262144   // 4 x [128][256]
#define OFF_WF 393216   // 4 x [128][128]
#define OFF_WE 458752   // [128][32]
#define OFF_WS 462848   // [128]

__device__ __forceinline__ float b2f(u16 v) {
    unsigned int u = ((unsigned int)v) << 16;
    float f;
    __builtin_memcpy(&f, &u, 4);
    return f;
}
__device__ __forceinline__ u16 f2b(float f) {
    __hip_bfloat16 h = __float2bfloat16(f);
    u16 u;
    __builtin_memcpy(&u, &h, 2);
    return u;
}
__device__ __forceinline__ short8 pack8(float4 a, float4 b) {
    short8 p;
    p[0] = (short)f2b(a.x); p[1] = (short)f2b(a.y);
    p[2] = (short)f2b(a.z); p[3] = (short)f2b(a.w);
    p[4] = (short)f2b(b.x); p[5] = (short)f2b(b.y);
    p[6] = (short)f2b(b.z); p[7] = (short)f2b(b.w);
    return p;
}

#define MFMA16(a, b, c) __builtin_amdgcn_mfma_f32_16x16x32_bf16(a, b, c, 0, 0, 0)

struct BiasP {
    const float* ba[4];
    const float* bb[4];
};

// LDS-tiled transpose prep: coalesced reads AND writes.
// grid: (18, 9). y 0..3 = Wa (256x256), y 4..7 = Wb (256x128), y 8 = Wf (545x128).
__global__ __launch_bounds__(256)
void prep_kernel(const float* __restrict__ W1a, const float* __restrict__ W2a,
                 const float* __restrict__ W3a, const float* __restrict__ W4a,
                 const float* __restrict__ W1b, const float* __restrict__ W2b,
                 const float* __restrict__ W3b, const float* __restrict__ W4b,
                 const float* __restrict__ Wf,  u16* __restrict__ ws) {
    __shared__ __align__(16) u16 T[64 * 80];

    const int y = blockIdx.y;
    const int t = threadIdx.x;
    const float* in;
    int K, N;
    if (y < 4)      { in = (y == 0) ? W1a : (y == 1) ? W2a : (y == 2) ? W3a : W4a; K = 256; N = 256; }
    else if (y < 8) { in = (y == 4) ? W1b : (y == 5) ? W2b : (y == 6) ? W3b : W4b; K = 256; N = 128; }
    else            { in = Wf; K = 545; N = 128; }

    const int ntilesN = N / 64;
    const int ktiles = (K + 63) / 64;
    const int kt = blockIdx.x / ntilesN;
    const int nt = blockIdx.x - kt * ntilesN;
    if (kt >= ktiles) return;
    const int kbase = kt * 64, nbase = nt * 64;

    // load 64k x 64n tile, coalesced over n
    {
        int tn = (t & 15) * 4;
        int tk = t >> 4;
        #pragma unroll
        for (int r = 0; r < 4; r++) {
            int k = kbase + tk + 16 * r;
            if (k < K) {
                float4 v = *(const float4*)(in + (size_t)k * N + nbase + tn);
                T[(tn + 0) * 80 + tk + 16 * r] = f2b(v.x);
                T[(tn + 1) * 80 + tk + 16 * r] = f2b(v.y);
                T[(tn + 2) * 80 + tk + 16 * r] = f2b(v.z);
                T[(tn + 3) * 80 + tk + 16 * r] = f2b(v.w);
            }
        }
    }
    __syncthreads();

    // write transposed, coalesced over k
    {
        int n = t >> 2;
        int kc = (t & 3) * 16;
        int n_out = nbase + n;
        const u16* src = &T[n * 80 + kc];
        if (y < 4) {
            u16* dst = ws + OFF_WA + y * 65536 + (size_t)n_out * 256 + kbase + kc;
            *(short8*)dst = *(const short8*)src;
            *(short8*)(dst + 8) = *(const short8*)(src + 8);
        } else if (y < 8) {
            u16* dst = ws + OFF_WB + (y - 4) * 32768 + (size_t)n_out * 256 + kbase + kc;
            *(short8*)dst = *(const short8*)src;
            *(short8*)(dst + 8) = *(const short8*)(src + 8);
        } else if (kbase < 512) {
            u16* dst = ws + OFF_WF + (kbase >> 7) * 16384 + (size_t)n_out * 128 + (kbase & 127) + kc;
            *(short8*)dst = *(const short8*)src;
            *(short8*)(dst + 8) = *(const short8*)(src + 8);
        } else {
            #pragma unroll
            for (int j = 0; j < 16; j++) {
                int k = kbase + kc + j;
                if (k < 545) {
                    u16 v = src[j];
                    if (k == 512)      ws[OFF_WS + n_out] = v;
                    else               ws[OFF_WE + n_out * 32 + (k - 513)] = v;
                }
            }
        }
    }
}

// 32 edges per block; LDS ~60 KB -> 2 blocks/CU (8 waves/CU).
// __launch_bounds__(256,2): 2 waves/SIMD needed -> 256-VGPR budget so the
// weight-load pipeline stays register-resident (r5's 100-VGPR allocation
// serialized every L2 load).
__global__ __launch_bounds__(256, 2)
void fused_kernel(const float* __restrict__ x, const int* __restrict__ ei,
                  const float* __restrict__ ea, const u16* __restrict__ ws,
                  BiasP bp, const float* __restrict__ bfp, float* __restrict__ out) {
    __shared__ __align__(16) u16 Xs[32][264];
    __shared__ __align__(16) u16 Xd[32][264];
    __shared__ __align__(16) u16 Hs[32][264];
    __shared__ __align__(16) u16 Gs[32][136];
    __shared__ float scos[32];

    const int t = threadIdx.x;
    const int wave = t >> 6;
    const int lane = t & 63;
    const int l15 = lane & 15;
    const int g = lane >> 4;
    const int e0 = blockIdx.x * 32;

    const f32x4 zero4 = {0.f, 0.f, 0.f, 0.f};

    // Hedge: detect int64 edge_index (sampled high words all zero) vs int32.
    bool idx64 = true;
    #pragma unroll
    for (int i = 1; i < 16; i += 2) { idx64 = idx64 && (ei[i] == 0); }

    // ---- gather (f32 -> bf16 tiles) + cosine similarity in one pass ----
    {
        int edge = t >> 3;            // 0..31
        int c = t & 7;                // 32-float chunk of the 256-row
        int pos = e0 + edge;
        int is = idx64 ? ei[2 * pos] : ei[pos];
        int id = idx64 ? ei[2 * (NE + pos)] : ei[NE + pos];
        const float* rs = x + (size_t)is * 256 + c * 32;
        const float* rd = x + (size_t)id * 256 + c * 32;
        float dot = 0.f, ss = 0.f, dd = 0.f;
        #pragma unroll
        for (int i = 0; i < 4; i++) {
            float4 s0 = *(const float4*)(rs + i * 8);
            float4 s1 = *(const float4*)(rs + i * 8 + 4);
            float4 d0 = *(const float4*)(rd + i * 8);
            float4 d1 = *(const float4*)(rd + i * 8 + 4);
            dot += s0.x * d0.x + s0.y * d0.y + s0.z * d0.z + s0.w * d0.w
                 + s1.x * d1.x + s1.y * d1.y + s1.z * d1.z + s1.w * d1.w;
            ss  += s0.x * s0.x + s0.y * s0.y + s0.z * s0.z + s0.w * s0.w
                 + s1.x * s1.x + s1.y * s1.y + s1.z * s1.z + s1.w * s1.w;
            dd  += d0.x * d0.x + d0.y * d0.y + d0.z * d0.z + d0.w * d0.w
                 + d1.x * d1.x + d1.y * d1.y + d1.z * d1.z + d1.w * d1.w;
            *(short8*)(&Xs[edge][c * 32 + i * 8]) = pack8(s0, s1);
            *(short8*)(&Xd[edge][c * 32 + i * 8]) = pack8(d0, d1);
        }
        dot += __shfl_xor(dot, 1); ss += __shfl_xor(ss, 1); dd += __shfl_xor(dd, 1);
        dot += __shfl_xor(dot, 2); ss += __shfl_xor(ss, 2); dd += __shfl_xor(dd, 2);
        dot += __shfl_xor(dot, 4); ss += __shfl_xor(ss, 4); dd += __shfl_xor(dd, 4);
        if (c == 0) {
            float ns = fmaxf(sqrtf(ss), 1e-8f);
            float nd = fmaxf(sqrtf(dd), 1e-8f);
            scos[edge] = dot / (ns * nd);
        }
    }
    __syncthreads();

    const int colA = wave * 64;   // stage A: wave owns 64 of 256 cols
    const int colC = wave * 32;   // stage B/C: wave owns 32 of 128 cols

    // ---- pre-issue long-lived fragments/constants (consumed after the m-loop) ----
    short8 eaA[2];
    #pragma unroll
    for (int mt = 0; mt < 2; mt++) {
        const float* er = ea + (size_t)(e0 + mt * 16 + l15) * 32 + g * 8;
        float4 a = *(const float4*)(er);
        float4 b = *(const float4*)(er + 4);
        eaA[mt] = pack8(a, b);
    }
    short8 eaB[2];
    float epi_b[2], epi_w[2];
    #pragma unroll
    for (int nt = 0; nt < 2; nt++) {
        int col = colC + nt * 16 + l15;
        eaB[nt] = *(const short8*)(ws + OFF_WE + col * 32 + g * 8);
        epi_b[nt] = bfp[col];
        epi_w[nt] = b2f(ws[OFF_WS + col]);
    }

    // ---- LDS read base pointers (immediate kk*64B offsets from here) ----
    const u16* xsb[2]; const u16* xdb[2]; const u16* hrb[2]; const u16* grb[2];
    #pragma unroll
    for (int mt = 0; mt < 2; mt++) {
        xsb[mt] = &Xs[mt * 16 + l15][g * 8];
        xdb[mt] = &Xd[mt * 16 + l15][g * 8];
        hrb[mt] = &Hs[mt * 16 + l15][g * 8];
        grb[mt] = &Gs[mt * 16 + l15][g * 8];
    }

    f32x4 Facc[2][2];
    #pragma unroll
    for (int a = 0; a < 2; a++) {
        #pragma unroll
        for (int b = 0; b < 2; b++) { Facc[a][b] = zero4; }
    }

    #pragma unroll 1
    for (int m = 0; m < 4; m++) {
        // ===== stage A: H = relu(A @ Wa + ba); A in {Xs, Xd, Xs-Xd, Xs*Xd} =====
        const u16* wan[4];
        #pragma unroll
        for (int nt = 0; nt < 4; nt++) {
            wan[nt] = ws + OFF_WA + m * 65536 + (size_t)(colA + nt * 16 + l15) * 256 + g * 8;
        }
        float biasA[4];
        #pragma unroll
        for (int nt = 0; nt < 4; nt++) { biasA[nt] = bp.ba[m][colA + nt * 16 + l15]; }

        f32x4 accA[2][4];
        #pragma unroll
        for (int a = 0; a < 2; a++) {
            #pragma unroll
            for (int b = 0; b < 4; b++) { accA[a][b] = zero4; }
        }

        // 4-deep weight pipeline (16 loads in flight) + depth-1 LDS A-frag prefetch.
        short8 wbufA[4][4];
        #pragma unroll
        for (int d = 0; d < 4; d++) {
            #pragma unroll
            for (int nt = 0; nt < 4; nt++) {
                wbufA[d][nt] = *(const short8*)(wan[nt] + d * 32);
            }
        }
        short8 rs_[2][2], rd_[2][2];
        if (m != 1) {
            rs_[0][0] = *(const short8*)(xsb[0]);
            rs_[0][1] = *(const short8*)(xsb[1]);
        }
        if (m != 0) {
            rd_[0][0] = *(const short8*)(xdb[0]);
            rd_[0][1] = *(const short8*)(xdb[1]);
        }
        #pragma unroll
        for (int kk = 0; kk < 8; kk++) {
            const int cur = kk & 3;
            const int pcur = kk & 1, pnxt = pcur ^ 1;
            if (kk < 7) {   // prefetch next LDS A-fragments
                if (m != 1) {
                    rs_[pnxt][0] = *(const short8*)(xsb[0] + (kk + 1) * 32);
                    rs_[pnxt][1] = *(const short8*)(xsb[1] + (kk + 1) * 32);
                }
                if (m != 0) {
                    rd_[pnxt][0] = *(const short8*)(xdb[0] + (kk + 1) * 32);
                    rd_[pnxt][1] = *(const short8*)(xdb[1] + (kk + 1) * 32);
                }
            }
            short8 af[2];
            if (m == 0) {
                af[0] = rs_[pcur][0]; af[1] = rs_[pcur][1];
            } else if (m == 1) {
                af[0] = rd_[pcur][0]; af[1] = rd_[pcur][1];
            } else {
                #pragma unroll
                for (int mt = 0; mt < 2; mt++) {
                    short8 s = rs_[pcur][mt], d = rd_[pcur][mt], rr;
                    #pragma unroll
                    for (int j = 0; j < 8; j++) {
                        float fs = b2f((u16)s[j]);
                        float fd = b2f((u16)d[j]);
                        rr[j] = (short)f2b((m == 2) ? (fs - fd) : (fs * fd));
                    }
                    af[mt] = rr;
                }
            }
            #pragma unroll
            for (int mt = 0; mt < 2; mt++) {
                #pragma unroll
                for (int nt = 0; nt < 4; nt++) {
                    accA[mt][nt] = MFMA16(af[mt], wbufA[cur][nt], accA[mt][nt]);
                }
            }
            if (kk < 4) {   // refill the slot just consumed with kk+4
                #pragma unroll
                for (int nt = 0; nt < 4; nt++) {
                    wbufA[cur][nt] = *(const short8*)(wan[nt] + (kk + 4) * 32);
                }
            }
        }
        #pragma unroll
        for (int nt = 0; nt < 4; nt++) {
            int col = colA + nt * 16 + l15;
            #pragma unroll
            for (int mt = 0; mt < 2; mt++) {
                #pragma unroll
                for (int rg = 0; rg < 4; rg++) {
                    int row = mt * 16 + g * 4 + rg;
                    Hs[row][col] = f2b(fmaxf(accA[mt][nt][rg] + biasA[nt], 0.f));
                }
            }
        }
        __syncthreads();

        // ===== stage B: G = relu(H @ Wb + bb) — full weight hoist (16 loads) =====
        {
            const u16* wbn[2];
            #pragma unroll
            for (int nt = 0; nt < 2; nt++) {
                wbn[nt] = ws + OFF_WB + m * 32768 + (size_t)(colC + nt * 16 + l15) * 256 + g * 8;
            }
            float biasB[2];
            #pragma unroll
            for (int nt = 0; nt < 2; nt++) { biasB[nt] = bp.bb[m][colC + nt * 16 + l15]; }

            short8 wB[8][2];
            #pragma unroll
            for (int kk = 0; kk < 8; kk++) {
                #pragma unroll
                for (int nt = 0; nt < 2; nt++) {
                    wB[kk][nt] = *(const short8*)(wbn[nt] + kk * 32);
                }
            }
            f32x4 accB[2][2];
            #pragma unroll
            for (int a = 0; a < 2; a++) {
                #pragma unroll
                for (int b = 0; b < 2; b++) { accB[a][b] = zero4; }
            }
            short8 hA[2][2];
            #pragma unroll
            for (int mt = 0; mt < 2; mt++) { hA[0][mt] = *(const short8*)(hrb[mt]); }
            #pragma unroll
            for (int kk = 0; kk < 8; kk++) {
                const int cur = kk & 1, nxt = cur ^ 1;
                if (kk < 7) {
                    #pragma unroll
                    for (int mt = 0; mt < 2; mt++) {
                        hA[nxt][mt] = *(const short8*)(hrb[mt] + (kk + 1) * 32);
                    }
                }
                #pragma unroll
                for (int mt = 0; mt < 2; mt++) {
                    #pragma unroll
                    for (int nt = 0; nt < 2; nt++) {
                        accB[mt][nt] = MFMA16(hA[cur][mt], wB[kk][nt], accB[mt][nt]);
                    }
                }
            }
            #pragma unroll
            for (int nt = 0; nt < 2; nt++) {
                int col = colC + nt * 16 + l15;
                #pragma unroll
                for (int mt = 0; mt < 2; mt++) {
                    #pragma unroll
                    for (int rg = 0; rg < 4; rg++) {
                        int row = mt * 16 + g * 4 + rg;
                        Gs[row][col] = f2b(fmaxf(accB[mt][nt][rg] + biasB[nt], 0.f));
                    }
                }
            }
        }
        __syncthreads();

        // ===== stage C: Facc += G @ WfT_m — full weight hoist (8 loads).
        // (no trailing barrier: next-A's barrier orders Gs reads vs next-B writes) =====
        {
            const u16* wfn[2];
            #pragma unroll
            for (int nt = 0; nt < 2; nt++) {
                wfn[nt] = ws + OFF_WF + m * 16384 + (size_t)(colC + nt * 16 + l15) * 128 + g * 8;
            }
            short8 wF[4][2];
            #pragma unroll
            for (int kk = 0; kk < 4; kk++) {
                #pragma unroll
                for (int nt = 0; nt < 2; nt++) {
                    wF[kk][nt] = *(const short8*)(wfn[nt] + kk * 32);
                }
            }
            short8 gA[2][2];
            #pragma unroll
            for (int mt = 0; mt < 2; mt++) { gA[0][mt] = *(const short8*)(grb[mt]); }
            #pragma unroll
            for (int kk = 0; kk < 4; kk++) {
                const int cur = kk & 1, nxt = cur ^ 1;
                if (kk < 3) {
                    #pragma unroll
                    for (int mt = 0; mt < 2; mt++) {
                        gA[nxt][mt] = *(const short8*)(grb[mt] + (kk + 1) * 32);
                    }
                }
                #pragma unroll
                for (int mt = 0; mt < 2; mt++) {
                    #pragma unroll
                    for (int nt = 0; nt < 2; nt++) {
                        Facc[mt][nt] = MFMA16(gA[cur][mt], wF[kk][nt], Facc[mt][nt]);
                    }
                }
            }
        }
    }

    // ===== edge_attr contribution: Facc += EA @ WeT (fragments pre-loaded) =====
    #pragma unroll
    for (int mt = 0; mt < 2; mt++) {
        #pragma unroll
        for (int nt = 0; nt < 2; nt++) {
            Facc[mt][nt] = MFMA16(eaA[mt], eaB[nt], Facc[mt][nt]);
        }
    }

    // ===== epilogue: + s*Wf[512] + bf, tanh, stage f32 in LDS, coalesced store =====
    float* os = (float*)&Xs[0][0];   // reuse Xs: 32 rows x 132 f32 = 16896 B (exact fit)
    #pragma unroll
    for (int nt = 0; nt < 2; nt++) {
        int col = colC + nt * 16 + l15;
        #pragma unroll
        for (int mt = 0; mt < 2; mt++) {
            #pragma unroll
            for (int rg = 0; rg < 4; rg++) {
                int row = mt * 16 + g * 4 + rg;
                float v = Facc[mt][nt][rg] + scos[row] * epi_w[nt] + epi_b[nt];
                v = fminf(fmaxf(v, -15.f), 15.f);
                float e2 = __expf(2.f * v);
                os[row * 132 + col] = (e2 - 1.f) / (e2 + 1.f);
            }
        }
    }
    __syncthreads();
    {
        int row = t >> 3, c = t & 7;
        float* op = out + (size_t)(e0 + row) * 128 + c * 16;
        const float* sp = os + row * 132 + c * 16;
        #pragma unroll
        for (int i = 0; i < 4; i++) {
            float4 v = *(const float4*)(sp + i * 4);
            *(float4*)(op + i * 4) = v;
        }
    }
}

extern "C" void kernel_launch(void* const* d_in, const int* in_sizes, int n_in,
                              void* d_out, int out_size, void* d_ws, size_t ws_size,
                              hipStream_t stream) {
    u16* ws = (u16*)d_ws;
    prep_kernel<<<dim3(18, 9), 256, 0, stream>>>(
        (const float*)d_in[3],  (const float*)d_in[7],  (const float*)d_in[11], (const float*)d_in[15],
        (const float*)d_in[5],  (const float*)d_in[9],  (const float*)d_in[13], (const float*)d_in[17],
        (const float*)d_in[19], ws);

    BiasP bp;
    bp.ba[0] = (const float*)d_in[4];  bp.ba[1] = (const float*)d_in[8];
    bp.ba[2] = (const float*)d_in[12]; bp.ba[3] = (const float*)d_in[16];
    bp.bb[0] = (const float*)d_in[6];  bp.bb[1] = (const float*)d_in[10];
    bp.bb[2] = (const float*)d_in[14]; bp.bb[3] = (const float*)d_in[18];

    fused_kernel<<<NE / 32, 256, 0, stream>>>(
        (const float*)d_in[0], (const int*)d_in[1], (const float*)d_in[2], ws,
        bp, (const float*)d_in[20], (float*)d_out);
}

// Round 7
// 487.052 us; speedup vs baseline: 2.5753x; 1.2567x over previous
//
#include <hip/hip_runtime.h>
#include <hip/hip_bf16.h>

typedef unsigned short u16;
typedef __attribute__((ext_vector_type(8))) short short8;
typedef __attribute__((ext_vector_type(4))) float f32x4;

#define NE 131072

// ws layout in u16 elements (bf16 transposed weights, [n][k] row-major)
#define OFF_WA 0        // 4 x [256][256]
#define OFF_WB 262144   // 4 x [128][256]
#define OFF_WF 393216   // 4 x [128][128]
#define OFF_WE 458752   // [128][32]
#define OFF_WS 462848   // [128]

// async global->LDS, 16B per lane, lane i lands at lds_base + 16*i
#define ASYNC16(gp, lp) __builtin_amdgcn_global_load_lds( \
    (const __attribute__((address_space(1))) unsigned int*)(gp), \
    (__attribute__((address_space(3))) unsigned int*)(lp), 16, 0, 0)
// wait lgkmcnt(0) only (vmcnt=63 no-wait, expcnt=7 no-wait): ensures ds_read data
// is in VGPRs before we overwrite the LDS region with the next DMA chunk.
#define LGKM0() __builtin_amdgcn_s_waitcnt(0xC07F)

__device__ __forceinline__ float b2f(u16 v) {
    unsigned int u = ((unsigned int)v) << 16;
    float f;
    __builtin_memcpy(&f, &u, 4);
    return f;
}
__device__ __forceinline__ u16 f2b(float f) {
    __hip_bfloat16 h = __float2bfloat16(f);
    u16 u;
    __builtin_memcpy(&u, &h, 2);
    return u;
}
__device__ __forceinline__ short8 pack8(float4 a, float4 b) {
    short8 p;
    p[0] = (short)f2b(a.x); p[1] = (short)f2b(a.y);
    p[2] = (short)f2b(a.z); p[3] = (short)f2b(a.w);
    p[4] = (short)f2b(b.x); p[5] = (short)f2b(b.y);
    p[6] = (short)f2b(b.z); p[7] = (short)f2b(b.w);
    return p;
}

#define MFMA16(a, b, c) __builtin_amdgcn_mfma_f32_16x16x32_bf16(a, b, c, 0, 0, 0)

struct BiasP {
    const float* ba[4];
    const float* bb[4];
};

// ---- per-wave async weight staging (each wave stages its own 4-KB quarter) ----
// Wb quarter layout, stage A (chunk = 32 k): [n_local(64)][32k] u16
__device__ __forceinline__ void issueA(const u16* ws, u16* Wb, int wave, int lane, int m, int kk) {
    const u16* gp = ws + OFF_WA + m * 65536
                  + (size_t)(wave * 64 + (lane >> 2)) * 256 + kk * 32 + (lane & 3) * 8;
    u16* lp = Wb + wave * 2048;
    #pragma unroll
    for (int j = 0; j < 4; j++) ASYNC16(gp + j * 4096, lp + j * 512);
}
// stage B (chunk = 64 k): [n_local(32)][8 slots of 8k, slot XOR-swizzled by n&7]
__device__ __forceinline__ void issueB(const u16* ws, u16* Wb, int wave, int lane, int m, int kc) {
    int nl = lane >> 3, sg = (lane & 7) ^ (nl & 7);
    const u16* gp = ws + OFF_WB + m * 32768
                  + (size_t)(wave * 32 + nl) * 256 + kc * 64 + sg * 8;
    u16* lp = Wb + wave * 2048;
    #pragma unroll
    for (int j = 0; j < 4; j++) ASYNC16(gp + j * 2048, lp + j * 512);
}
__device__ __forceinline__ void issueC(const u16* ws, u16* Wb, int wave, int lane, int m, int kc) {
    int nl = lane >> 3, sg = (lane & 7) ^ (nl & 7);
    const u16* gp = ws + OFF_WF + m * 16384
                  + (size_t)(wave * 32 + nl) * 128 + kc * 64 + sg * 8;
    u16* lp = Wb + wave * 2048;
    #pragma unroll
    for (int j = 0; j < 4; j++) ASYNC16(gp + j * 1024, lp + j * 512);
}

// LDS-tiled transpose prep: coalesced reads AND writes.
__global__ __launch_bounds__(256)
void prep_kernel(const float* __restrict__ W1a, const float* __restrict__ W2a,
                 const float* __restrict__ W3a, const float* __restrict__ W4a,
                 const float* __restrict__ W1b, const float* __restrict__ W2b,
                 const float* __restrict__ W3b, const float* __restrict__ W4b,
                 const float* __restrict__ Wf,  u16* __restrict__ ws) {
    __shared__ __align__(16) u16 T[64 * 80];

    const int y = blockIdx.y;
    const int t = threadIdx.x;
    const float* in;
    int K, N;
    if (y < 4)      { in = (y == 0) ? W1a : (y == 1) ? W2a : (y == 2) ? W3a : W4a; K = 256; N = 256; }
    else if (y < 8) { in = (y == 4) ? W1b : (y == 5) ? W2b : (y == 6) ? W3b : W4b; K = 256; N = 128; }
    else            { in = Wf; K = 545; N = 128; }

    const int ntilesN = N / 64;
    const int ktiles = (K + 63) / 64;
    const int kt = blockIdx.x / ntilesN;
    const int nt = blockIdx.x - kt * ntilesN;
    if (kt >= ktiles) return;
    const int kbase = kt * 64, nbase = nt * 64;

    {
        int tn = (t & 15) * 4;
        int tk = t >> 4;
        #pragma unroll
        for (int r = 0; r < 4; r++) {
            int k = kbase + tk + 16 * r;
            if (k < K) {
                float4 v = *(const float4*)(in + (size_t)k * N + nbase + tn);
                T[(tn + 0) * 80 + tk + 16 * r] = f2b(v.x);
                T[(tn + 1) * 80 + tk + 16 * r] = f2b(v.y);
                T[(tn + 2) * 80 + tk + 16 * r] = f2b(v.z);
                T[(tn + 3) * 80 + tk + 16 * r] = f2b(v.w);
            }
        }
    }
    __syncthreads();
    {
        int n = t >> 2;
        int kc = (t & 3) * 16;
        int n_out = nbase + n;
        const u16* src = &T[n * 80 + kc];
        if (y < 4) {
            u16* dst = ws + OFF_WA + y * 65536 + (size_t)n_out * 256 + kbase + kc;
            *(short8*)dst = *(const short8*)src;
            *(short8*)(dst + 8) = *(const short8*)(src + 8);
        } else if (y < 8) {
            u16* dst = ws + OFF_WB + (y - 4) * 32768 + (size_t)n_out * 256 + kbase + kc;
            *(short8*)dst = *(const short8*)src;
            *(short8*)(dst + 8) = *(const short8*)(src + 8);
        } else if (kbase < 512) {
            u16* dst = ws + OFF_WF + (kbase >> 7) * 16384 + (size_t)n_out * 128 + (kbase & 127) + kc;
            *(short8*)dst = *(const short8*)src;
            *(short8*)(dst + 8) = *(const short8*)(src + 8);
        } else {
            #pragma unroll
            for (int j = 0; j < 16; j++) {
                int k = kbase + kc + j;
                if (k < 545) {
                    u16 v = src[j];
                    if (k == 512)      ws[OFF_WS + n_out] = v;
                    else               ws[OFF_WE + n_out * 32 + (k - 513)] = v;
                }
            }
        }
    }
}

// 32 edges/block, 4 waves, ~74 KB LDS -> 2 blocks/CU.
// Weights: L2 -> LDS via global_load_lds (zero VGPR cost, deep flight),
// one __syncthreads per chunk; each chunk's DMA issued one phase early.
__global__ __launch_bounds__(256, 2)
void fused_kernel(const float* __restrict__ x, const int* __restrict__ ei,
                  const float* __restrict__ ea, const u16* __restrict__ ws,
                  BiasP bp, const float* __restrict__ bfp, float* __restrict__ out) {
    __shared__ __align__(16) u16 Xs[32][264];
    __shared__ __align__(16) u16 Xd[32][264];
    __shared__ __align__(16) u16 Hs[32][264];
    __shared__ __align__(16) u16 Gs[32][136];
    __shared__ __align__(16) u16 Wb[8192];   // 16 KB, 4-KB quarter per wave
    __shared__ float scos[32];

    const int t = threadIdx.x;
    const int wave = t >> 6;
    const int lane = t & 63;
    const int l15 = lane & 15;
    const int g = lane >> 4;
    const int e0 = blockIdx.x * 32;
    const f32x4 zero4 = {0.f, 0.f, 0.f, 0.f};

    // Hedge: detect int64 edge_index (sampled high words all zero) vs int32.
    bool idx64 = true;
    #pragma unroll
    for (int i = 1; i < 16; i += 2) { idx64 = idx64 && (ei[i] == 0); }

    // fire the first weight chunk now; it lands during the gather
    issueA(ws, Wb, wave, lane, 0, 0);

    // ---- gather (f32 -> bf16 tiles) + cosine similarity in one pass ----
    {
        int edge = t >> 3;
        int c = t & 7;
        int pos = e0 + edge;
        int is = idx64 ? ei[2 * pos] : ei[pos];
        int id = idx64 ? ei[2 * (NE + pos)] : ei[NE + pos];
        const float* rs = x + (size_t)is * 256 + c * 32;
        const float* rd = x + (size_t)id * 256 + c * 32;
        float dot = 0.f, ss = 0.f, dd = 0.f;
        #pragma unroll
        for (int i = 0; i < 4; i++) {
            float4 s0 = *(const float4*)(rs + i * 8);
            float4 s1 = *(const float4*)(rs + i * 8 + 4);
            float4 d0 = *(const float4*)(rd + i * 8);
            float4 d1 = *(const float4*)(rd + i * 8 + 4);
            dot += s0.x * d0.x + s0.y * d0.y + s0.z * d0.z + s0.w * d0.w
                 + s1.x * d1.x + s1.y * d1.y + s1.z * d1.z + s1.w * d1.w;
            ss  += s0.x * s0.x + s0.y * s0.y + s0.z * s0.z + s0.w * s0.w
                 + s1.x * s1.x + s1.y * s1.y + s1.z * s1.z + s1.w * s1.w;
            dd  += d0.x * d0.x + d0.y * d0.y + d0.z * d0.z + d0.w * d0.w
                 + d1.x * d1.x + d1.y * d1.y + d1.z * d1.z + d1.w * d1.w;
            *(short8*)(&Xs[edge][c * 32 + i * 8]) = pack8(s0, s1);
            *(short8*)(&Xd[edge][c * 32 + i * 8]) = pack8(d0, d1);
        }
        dot += __shfl_xor(dot, 1); ss += __shfl_xor(ss, 1); dd += __shfl_xor(dd, 1);
        dot += __shfl_xor(dot, 2); ss += __shfl_xor(ss, 2); dd += __shfl_xor(dd, 2);
        dot += __shfl_xor(dot, 4); ss += __shfl_xor(ss, 4); dd += __shfl_xor(dd, 4);
        if (c == 0) {
            float ns = fmaxf(sqrtf(ss), 1e-8f);
            float nd = fmaxf(sqrtf(dd), 1e-8f);
            scos[edge] = dot / (ns * nd);
        }
    }
    // (no barrier here: the first chunk barrier below covers gather + DMA)

    const int colA = wave * 64;
    const int colC = wave * 32;

    // ---- hoisted constants (all global loads live before the m-loop) ----
    short8 eaA[2];
    #pragma unroll
    for (int mt = 0; mt < 2; mt++) {
        const float* er = ea + (size_t)(e0 + mt * 16 + l15) * 32 + g * 8;
        float4 a = *(const float4*)(er);
        float4 b = *(const float4*)(er + 4);
        eaA[mt] = pack8(a, b);
    }
    short8 eaB[2];
    float epi_b[2], epi_w[2];
    #pragma unroll
    for (int nt = 0; nt < 2; nt++) {
        int col = colC + nt * 16 + l15;
        eaB[nt] = *(const short8*)(ws + OFF_WE + col * 32 + g * 8);
        epi_b[nt] = bfp[col];
        epi_w[nt] = b2f(ws[OFF_WS + col]);
    }
    float biasA[4][4], biasB[4][2];
    #pragma unroll
    for (int m = 0; m < 4; m++) {
        #pragma unroll
        for (int nt = 0; nt < 4; nt++) biasA[m][nt] = bp.ba[m][colA + nt * 16 + l15];
        #pragma unroll
        for (int nt = 0; nt < 2; nt++) biasB[m][nt] = bp.bb[m][colC + nt * 16 + l15];
    }

    // ---- LDS read base pointers ----
    const u16* xsb0 = &Xs[l15][g * 8];      const u16* xsb1 = &Xs[16 + l15][g * 8];
    const u16* xdb0 = &Xd[l15][g * 8];      const u16* xdb1 = &Xd[16 + l15][g * 8];
    const u16* hrb0 = &Hs[l15][g * 8];      const u16* hrb1 = &Hs[16 + l15][g * 8];
    const u16* grb0 = &Gs[l15][g * 8];      const u16* grb1 = &Gs[16 + l15][g * 8];
    const u16* wba  = Wb + wave * 2048 + l15 * 32 + g * 8;    // stage A frags
    const u16* wbb  = Wb + wave * 2048 + l15 * 64;            // stage B/C frags

    f32x4 Facc[2][2];
    #pragma unroll
    for (int a = 0; a < 2; a++) {
        #pragma unroll
        for (int b = 0; b < 2; b++) Facc[a][b] = zero4;
    }

    #pragma unroll
    for (int m = 0; m < 4; m++) {
        // ===== stage A: H = relu(A @ Wa + ba) ===== (8 chunks of 32-k)
        f32x4 accA[2][4];
        #pragma unroll
        for (int a = 0; a < 2; a++) {
            #pragma unroll
            for (int b = 0; b < 4; b++) accA[a][b] = zero4;
        }
        #pragma unroll
        for (int kk = 0; kk < 8; kk++) {
            __syncthreads();                     // chunk kk landed (+ gather on first)
            short8 wf[4];
            #pragma unroll
            for (int nt = 0; nt < 4; nt++) wf[nt] = *(const short8*)(wba + nt * 512);
            short8 s0, s1, d0, d1;
            if (m != 1) { s0 = *(const short8*)(xsb0 + kk * 32); s1 = *(const short8*)(xsb1 + kk * 32); }
            if (m != 0) { d0 = *(const short8*)(xdb0 + kk * 32); d1 = *(const short8*)(xdb1 + kk * 32); }
            LGKM0();                             // frag data in regs before overwrite
            if (kk < 7) issueA(ws, Wb, wave, lane, m, kk + 1);
            else        issueB(ws, Wb, wave, lane, m, 0);
            short8 af[2];
            if (m == 0)      { af[0] = s0; af[1] = s1; }
            else if (m == 1) { af[0] = d0; af[1] = d1; }
            else {
                #pragma unroll
                for (int mt = 0; mt < 2; mt++) {
                    short8 s = mt ? s1 : s0, d = mt ? d1 : d0, rr;
                    #pragma unroll
                    for (int j = 0; j < 8; j++) {
                        float fs = b2f((u16)s[j]);
                        float fd = b2f((u16)d[j]);
                        rr[j] = (short)f2b((m == 2) ? (fs - fd) : (fs * fd));
                    }
                    af[mt] = rr;
                }
            }
            #pragma unroll
            for (int mt = 0; mt < 2; mt++) {
                #pragma unroll
                for (int nt = 0; nt < 4; nt++) {
                    accA[mt][nt] = MFMA16(af[mt], wf[nt], accA[mt][nt]);
                }
            }
        }
        #pragma unroll
        for (int nt = 0; nt < 4; nt++) {
            int col = colA + nt * 16 + l15;
            #pragma unroll
            for (int mt = 0; mt < 2; mt++) {
                #pragma unroll
                for (int rg = 0; rg < 4; rg++) {
                    int row = mt * 16 + g * 4 + rg;
                    Hs[row][col] = f2b(fmaxf(accA[mt][nt][rg] + biasA[m][nt], 0.f));
                }
            }
        }

        // ===== stage B: G = relu(H @ Wb + bb) ===== (4 chunks of 64-k)
        f32x4 accB[2][2];
        #pragma unroll
        for (int a = 0; a < 2; a++) {
            #pragma unroll
            for (int b = 0; b < 2; b++) accB[a][b] = zero4;
        }
        #pragma unroll
        for (int kc = 0; kc < 4; kc++) {
            __syncthreads();                     // chunk landed + (kc==0) Hs ready
            short8 wf[2][2], hf[2][2];
            #pragma unroll
            for (int kk2 = 0; kk2 < 2; kk2++) {
                const int slot = ((kk2 * 4 + g) ^ (l15 & 7)) * 8;
                wf[kk2][0] = *(const short8*)(wbb + slot);
                wf[kk2][1] = *(const short8*)(wbb + 1024 + slot);
                hf[kk2][0] = *(const short8*)(hrb0 + kc * 64 + kk2 * 32);
                hf[kk2][1] = *(const short8*)(hrb1 + kc * 64 + kk2 * 32);
            }
            LGKM0();
            if (kc < 3) issueB(ws, Wb, wave, lane, m, kc + 1);
            else        issueC(ws, Wb, wave, lane, m, 0);
            #pragma unroll
            for (int kk2 = 0; kk2 < 2; kk2++) {
                #pragma unroll
                for (int mt = 0; mt < 2; mt++) {
                    #pragma unroll
                    for (int nt = 0; nt < 2; nt++) {
                        accB[mt][nt] = MFMA16(hf[kk2][mt], wf[kk2][nt], accB[mt][nt]);
                    }
                }
            }
        }
        #pragma unroll
        for (int nt = 0; nt < 2; nt++) {
            int col = colC + nt * 16 + l15;
            #pragma unroll
            for (int mt = 0; mt < 2; mt++) {
                #pragma unroll
                for (int rg = 0; rg < 4; rg++) {
                    int row = mt * 16 + g * 4 + rg;
                    Gs[row][col] = f2b(fmaxf(accB[mt][nt][rg] + biasB[m][nt], 0.f));
                }
            }
        }

        // ===== stage C: Facc += G @ WfT_m ===== (2 chunks of 64-k)
        #pragma unroll
        for (int kc = 0; kc < 2; kc++) {
            __syncthreads();                     // chunk landed + (kc==0) Gs ready
            short8 wf[2][2], gf[2][2];
            #pragma unroll
            for (int kk2 = 0; kk2 < 2; kk2++) {
                const int slot = ((kk2 * 4 + g) ^ (l15 & 7)) * 8;
                wf[kk2][0] = *(const short8*)(wbb + slot);
                wf[kk2][1] = *(const short8*)(wbb + 1024 + slot);
                gf[kk2][0] = *(const short8*)(grb0 + kc * 64 + kk2 * 32);
                gf[kk2][1] = *(const short8*)(grb1 + kc * 64 + kk2 * 32);
            }
            LGKM0();
            if (kc == 0)     issueC(ws, Wb, wave, lane, m, 1);
            else if (m < 3)  issueA(ws, Wb, wave, lane, m + 1, 0);
            #pragma unroll
            for (int kk2 = 0; kk2 < 2; kk2++) {
                #pragma unroll
                for (int mt = 0; mt < 2; mt++) {
                    #pragma unroll
                    for (int nt = 0; nt < 2; nt++) {
                        Facc[mt][nt] = MFMA16(gf[kk2][mt], wf[kk2][nt], Facc[mt][nt]);
                    }
                }
            }
        }
    }

    // ===== edge_attr contribution (fragments pre-loaded) =====
    #pragma unroll
    for (int mt = 0; mt < 2; mt++) {
        #pragma unroll
        for (int nt = 0; nt < 2; nt++) {
            Facc[mt][nt] = MFMA16(eaA[mt], eaB[nt], Facc[mt][nt]);
        }
    }

    // ===== epilogue: + s*Wf[512] + bf, tanh, stage f32 in LDS, coalesced store =====
    float* os = (float*)&Xs[0][0];   // reuse Xs: 32 x 132 f32 = 16896 B (exact fit)
    #pragma unroll
    for (int nt = 0; nt < 2; nt++) {
        int col = colC + nt * 16 + l15;
        #pragma unroll
        for (int mt = 0; mt < 2; mt++) {
            #pragma unroll
            for (int rg = 0; rg < 4; rg++) {
                int row = mt * 16 + g * 4 + rg;
                float v = Facc[mt][nt][rg] + scos[row] * epi_w[nt] + epi_b[nt];
                v = fminf(fmaxf(v, -15.f), 15.f);
                float e2 = __expf(2.f * v);
                os[row * 132 + col] = (e2 - 1.f) / (e2 + 1.f);
            }
        }
    }
    __syncthreads();
    {
        int row = t >> 3, c = t & 7;
        float* op = out + (size_t)(e0 + row) * 128 + c * 16;
        const float* sp = os + row * 132 + c * 16;
        #pragma unroll
        for (int i = 0; i < 4; i++) {
            float4 v = *(const float4*)(sp + i * 4);
            *(float4*)(op + i * 4) = v;
        }
    }
}

extern "C" void kernel_launch(void* const* d_in, const int* in_sizes, int n_in,
                              void* d_out, int out_size, void* d_ws, size_t ws_size,
                              hipStream_t stream) {
    u16* ws = (u16*)d_ws;
    prep_kernel<<<dim3(18, 9), 256, 0, stream>>>(
        (const float*)d_in[3],  (const float*)d_in[7],  (const float*)d_in[11], (const float*)d_in[15],
        (const float*)d_in[5],  (const float*)d_in[9],  (const float*)d_in[13], (const float*)d_in[17],
        (const float*)d_in[19], ws);

    BiasP bp;
    bp.ba[0] = (const float*)d_in[4];  bp.ba[1] = (const float*)d_in[8];
    bp.ba[2] = (const float*)d_in[12]; bp.ba[3] = (const float*)d_in[16];
    bp.bb[0] = (const float*)d_in[6];  bp.bb[1] = (const float*)d_in[10];
    bp.bb[2] = (const float*)d_in[14]; bp.bb[3] = (const float*)d_in[18];

    fused_kernel<<<NE / 32, 256, 0, stream>>>(
        (const float*)d_in[0], (const int*)d_in[1], (const float*)d_in[2], ws,
        bp, (const float*)d_in[20], (float*)d_out);
}